// Round 7
// baseline (218.146 us; speedup 1.0000x reference)
//
#include <hip/hip_runtime.h>

#define LATENT 128
#define HIDDEN 256
#define OUTD   128
#define TT     100
#define DECH   64
#define NMACRO 7    // RK4 macro-steps of 16 grid intervals (last = 3)

typedef _Float16 f16x8 __attribute__((ext_vector_type(8)));
typedef float    f32x4 __attribute__((ext_vector_type(4)));

#define MFMA16(a,b,c) __builtin_amdgcn_mfma_f32_16x16x32_f16((a),(b),(c),0,0,0)

__device__ __forceinline__ float tanh_fast(float x){
    float e = __expf(2.f*x);
    return 1.f - 2.f*__builtin_amdgcn_rcpf(e + 1.f);
}

__device__ __forceinline__ f16x8 lds_rd8(const _Float16* b, int sB, int row, int colE){
    int off = row*sB + colE*2; off ^= (row&7)<<4;
    return *(const f16x8*)((const char*)b + off);
}
__device__ __forceinline__ void lds_wr1(_Float16* b, int sB, int row, int colE, float v){
    int off = row*sB + colE*2; off ^= (row&7)<<4;
    *(_Float16*)((char*)b + off) = (_Float16)v;
}

// B-frag gather from row-major fp32 W[K][N]: lane holds B[k0+8*(lane>>4)+i][n]
__device__ __forceinline__ f16x8 gbl_bfrag(const float* W, int ldN, int k0, int n){
    f16x8 f;
#pragma unroll
    for(int i=0;i<8;++i) f[i] = (_Float16)W[(size_t)(k0+i)*ldN + n];
    return f;
}

__global__ __launch_bounds__(512, 1) void ode_decoder_kernel(
    const float* __restrict__ z0, const float* __restrict__ times,
    const float* __restrict__ W1, const float* __restrict__ b1,
    const float* __restrict__ W2, const float* __restrict__ b2,
    const float* __restrict__ dW1, const float* __restrict__ db1,
    const float* __restrict__ dW2, const float* __restrict__ db2,
    const float* __restrict__ dW3, const float* __restrict__ db3,
    float* __restrict__ out)
{
    __shared__ _Float16 z_lds[16*LATENT]  __attribute__((aligned(16))); // 4 KB
    __shared__ _Float16 h_lds[16*HIDDEN]  __attribute__((aligned(16))); // 8 KB
    __shared__ _Float16 zint [128*LATENT] __attribute__((aligned(16))); // 32 KB (8 pts x 16 rows)
    __shared__ _Float16 h12s [8*16*DECH]  __attribute__((aligned(16))); // 16 KB per-wave scratch
    __shared__ _Float16 dw1c [16*64*8]    __attribute__((aligned(16))); // 16 KB dW1 frag cache
    __shared__ _Float16 dw3c [16*64*8]    __attribute__((aligned(16))); // 16 KB dW3 frag cache
    __shared__ float    tl[TT];

    const int tid  = threadIdx.x;
    const int wv   = tid >> 6;      // 0..7
    const int lane = tid & 63;
    const int lr   = lane & 15;
    const int lg   = lane >> 4;
    const int row0 = 4*lg;
    const int gRow0 = blockIdx.x * 16;
    _Float16* h12 = h12s + (size_t)wv*16*DECH;

    if(tid < TT) tl[tid] = times[tid];

    // ---------- chain weights in VGPRs (R4-verified 8-wave layout) ----------
    f16x8 w1f[2][4];
#pragma unroll
    for(int t=0;t<2;++t)
#pragma unroll
        for(int q=0;q<4;++q)
            w1f[t][q] = gbl_bfrag(W1, HIDDEN, 32*q+8*lg, 32*wv+16*t+lr);
    f16x8 w2f[8];
#pragma unroll
    for(int q=0;q<8;++q)
        w2f[q] = gbl_bfrag(W2, LATENT, 32*q+8*lg, 16*wv+lr);

    // ---------- decoder weights: dW2 in VGPRs; dW1/dW3 -> LDS frag caches ----------
    f16x8 dw2B[4][2];
#pragma unroll
    for(int n=0;n<4;++n)
#pragma unroll
        for(int q=0;q<2;++q)
            dw2B[n][q] = gbl_bfrag(dW2, DECH, 32*q+8*lg, 16*n+lr);
    {
#pragma unroll
        for(int ff=0;ff<2;++ff){
            int f = wv + 8*ff;
            int n1 = f>>2, q1 = f&3;
            *(f16x8*)(dw1c + ((size_t)f*64+lane)*8) = gbl_bfrag(dW1, DECH, 32*q1+8*lg, 16*n1+lr);
            int n3 = f>>1, q3 = f&1;
            *(f16x8*)(dw3c + ((size_t)f*64+lane)*8) = gbl_bfrag(dW3, OUTD, 32*q3+8*lg, 16*n3+lr);
        }
    }

    const float b1v0 = b1[32*wv+lr], b1v1 = b1[32*wv+16+lr];
    const float b2v  = b2[16*wv+lr];
    float db1n[4], db2n[4], db3n[8];
#pragma unroll
    for(int n=0;n<4;++n){ db1n[n] = db1[16*n+lr]; db2n[n] = db2[16*n+lr]; }
#pragma unroll
    for(int n=0;n<8;++n) db3n[n] = db3[16*n+lr];

    // ---------- state: lane owns z[row0+r][16*wv+lr] ----------
    f32x4 z, acc = {0,0,0,0};
    f32x4 zA = {0,0,0,0}, fA = {0,0,0,0}, fN = {0,0,0,0};
#pragma unroll
    for(int r=0;r<4;++r){
        z[r] = z0[(size_t)(gRow0+row0+r)*LATENT + 16*wv + lr];
        lds_wr1(z_lds, LATENT*2, row0+r, 16*wv+lr, z[r]);
    }
    __syncthreads();

    // ---------- chain segment bodies ----------
    auto G1SEG = [&]{
        f16x8 az[4];
#pragma unroll
        for(int q=0;q<4;++q) az[q] = lds_rd8(z_lds, LATENT*2, lr, 32*q+8*lg);
        f32x4 c0 = {b1v0,b1v0,b1v0,b1v0};
        f32x4 c1 = {b1v1,b1v1,b1v1,b1v1};
#pragma unroll
        for(int q=0;q<4;++q){ c0 = MFMA16(az[q], w1f[0][q], c0); c1 = MFMA16(az[q], w1f[1][q], c1); }
#pragma unroll
        for(int r=0;r<4;++r){
            lds_wr1(h_lds, HIDDEN*2, row0+r, 32*wv+lr,    tanh_fast(c0[r]));
            lds_wr1(h_lds, HIDDEN*2, row0+r, 32*wv+16+lr, tanh_fast(c1[r]));
        }
    };
    auto G2SEG = [&]() -> f32x4 {
        f16x8 ah[8];
#pragma unroll
        for(int q=0;q<8;++q) ah[q] = lds_rd8(h_lds, HIDDEN*2, lr, 32*q+8*lg);
        f32x4 ca = {b2v,b2v,b2v,b2v}, cb = {0,0,0,0};
#pragma unroll
        for(int q=0;q<4;++q){ ca = MFMA16(ah[q], w2f[q], ca); cb = MFMA16(ah[4+q], w2f[4+q], cb); }
        return ca + cb;
    };
    auto WRZ = [&](f32x4 zs){
#pragma unroll
        for(int r=0;r<4;++r) lds_wr1(z_lds, LATENT*2, row0+r, 16*wv+lr, zs[r]);
    };
    // Hermite dense output: npts points basePt.. of interval [t0,t0+hp] -> zint (pt i at rows 16i..)
    auto INTERPN = [&](int basePt, int npts, float t0, float hp, float rhp, f32x4 f1){
#pragma unroll
        for(int i=0;i<npts;++i){
            float th = (tl[basePt+i]-t0)*rhp;
            float t2 = th*th, t3 = t2*th;
            float a0 = 2.f*t3-3.f*t2+1.f, a1 = (t3-2.f*t2+th)*hp;
            float a2 = 3.f*t2-2.f*t3,     a3 = (t3-t2)*hp;
#pragma unroll
            for(int r=0;r<4;++r){
                float v = a0*zA[r] + a1*fA[r] + a2*z[r] + a3*f1[r];
                lds_wr1(zint, LATENT*2, 16*i+row0+r, 16*wv+lr, v);
            }
        }
    };
    // ---------- wave-local decode of one grid point (t-pt = wv of current round) ----------
    auto DCH1 = [&]{   // zint(t-pt wv) @ dW1 -> relu -> h12 (wave-local)
        f32x4 d1[4];
#pragma unroll
        for(int n=0;n<4;++n) d1[n] = (f32x4){db1n[n],db1n[n],db1n[n],db1n[n]};
#pragma unroll
        for(int q=0;q<4;++q){
            f16x8 a = lds_rd8(zint, LATENT*2, 16*wv+lr, 32*q+8*lg);
#pragma unroll
            for(int n=0;n<4;++n)
                d1[n] = MFMA16(a, *(const f16x8*)(dw1c + ((size_t)(n*4+q)*64+lane)*8), d1[n]);
        }
#pragma unroll
        for(int n=0;n<4;++n)
#pragma unroll
            for(int r=0;r<4;++r)
                lds_wr1(h12, DECH*2, row0+r, 16*n+lr, fmaxf(d1[n][r],0.f));
    };
    auto DCH2 = [&]{   // h12 @ dW2 -> relu -> h12 (overwrite, same wave, in-order DS)
        f32x4 d2[4];
#pragma unroll
        for(int n=0;n<4;++n) d2[n] = (f32x4){db2n[n],db2n[n],db2n[n],db2n[n]};
#pragma unroll
        for(int q=0;q<2;++q){
            f16x8 a = lds_rd8(h12, DECH*2, lr, 32*q+8*lg);
#pragma unroll
            for(int n=0;n<4;++n) d2[n] = MFMA16(a, dw2B[n][q], d2[n]);
        }
#pragma unroll
        for(int n=0;n<4;++n)
#pragma unroll
            for(int r=0;r<4;++r)
                lds_wr1(h12, DECH*2, row0+r, 16*n+lr, fmaxf(d2[n][r],0.f));
    };
    auto DCH3 = [&](int pt){   // h12 @ dW3 + db3 -> out[:, pt, :]
        f32x4 d3[8];
#pragma unroll
        for(int n=0;n<8;++n) d3[n] = (f32x4){db3n[n],db3n[n],db3n[n],db3n[n]};
#pragma unroll
        for(int q=0;q<2;++q){
            f16x8 a = lds_rd8(h12, DECH*2, lr, 32*q+8*lg);
#pragma unroll
            for(int n=0;n<8;++n)
                d3[n] = MFMA16(a, *(const f16x8*)(dw3c + ((size_t)(n*2+q)*64+lane)*8), d3[n]);
        }
#pragma unroll
        for(int n=0;n<8;++n)
#pragma unroll
            for(int r=0;r<4;++r)
                out[(size_t)(gRow0+row0+r)*TT*OUTD + (size_t)pt*OUTD + 16*n+lr] = d3[n][r];
    };

    // ---------- main: 7 macro RK4 steps; decode interval j-1 (16 pts, 2 rounds) during step j ----------
#pragma unroll 1
    for(int j=0;j<NMACRO;++j){
        const int  m0 = 16*j;
        const int  m1 = (m0+16 < TT-1) ? m0+16 : TT-1;
        const float hj = tl[m1]-tl[m0];
        const bool dec   = (j>=1);
        const bool dec3p = (j>=2);
        const int  pA = 16*(j-1);
        const float t0  = dec ? tl[pA] : 1.f;
        const float hp  = dec ? (tl[m0]-t0) : 1.f;
        const float rhp = 1.f/hp;

        // st0a
        G1SEG(); if(dec3p) DCH3(16*(j-2)+8+wv);
        __syncthreads();
        // st0b
        {
            f32x4 k1 = G2SEG();
            fN = k1;
            if(dec) INTERPN(pA, 8, t0, hp, rhp, k1);
            acc = z + k1*(hj*(1.f/6.f));
            WRZ(z + k1*(hj*0.5f));
        }
        __syncthreads();
        // st1a
        G1SEG(); if(dec) DCH1();
        __syncthreads();
        // st1b
        {
            f32x4 k2 = G2SEG(); if(dec) DCH2();
            acc += k2*(hj*(1.f/3.f));
            WRZ(z + k2*(hj*0.5f));
        }
        __syncthreads();
        // st2a
        G1SEG(); if(dec) DCH3(pA+wv);
        __syncthreads();
        // st2b
        {
            f32x4 k3 = G2SEG();
            if(dec) INTERPN(pA+8, 8, t0, hp, rhp, fN);
            zA = z; fA = fN;                       // after last use of old endpoints
            acc += k3*(hj*(1.f/3.f));
            WRZ(z + k3*hj);
        }
        __syncthreads();
        // st3a
        G1SEG(); if(dec) DCH1();
        __syncthreads();
        // st3b
        {
            f32x4 k4 = G2SEG(); if(dec) DCH2();
            z = acc + k4*(hj*(1.f/6.f));
            WRZ(z);
        }
        __syncthreads();
    }

    // ---------- tail ----------
    // pending: DCH3+store of round B of macro NMACRO-1 (pts 88..95)
    G1SEG(); DCH3(16*(NMACRO-2)+8+wv);
    __syncthreads();
    {
        f32x4 k1 = G2SEG();      // f(z_end) for last interval's Hermite
        const int b = 16*(NMACRO-1);
        const float t0t = tl[b], hpt = tl[TT-1]-t0t, rhpt = 1.f/hpt;
        INTERPN(b, 4, t0t, hpt, rhpt, k1);   // pts 96..99
    }
    __syncthreads();
    if(wv < 4){
        DCH1();
        DCH2();
        DCH3(16*(NMACRO-1)+wv);
    }
}

extern "C" void kernel_launch(void* const* d_in, const int* in_sizes, int n_in,
                              void* d_out, int out_size, void* d_ws, size_t ws_size,
                              hipStream_t stream) {
    ode_decoder_kernel<<<dim3(256), dim3(512), 0, stream>>>(
        (const float*)d_in[0],  (const float*)d_in[1],
        (const float*)d_in[2],  (const float*)d_in[3],
        (const float*)d_in[4],  (const float*)d_in[5],
        (const float*)d_in[6],  (const float*)d_in[7],
        (const float*)d_in[8],  (const float*)d_in[9],
        (const float*)d_in[10], (const float*)d_in[11],
        (float*)d_out);
}

// Round 8
// 73.036 us; speedup vs baseline: 2.9868x; 2.9868x over previous
//
#include <hip/hip_runtime.h>

#define LATENT 128
#define HIDDEN 256
#define OUTD   128
#define TT     100
#define DECH   64
#define NMACRO 7    // RK4 macro-steps of 16 grid intervals (last = 3)

typedef _Float16 f16x8 __attribute__((ext_vector_type(8)));
typedef float    f32x4 __attribute__((ext_vector_type(4)));

#define MFMA16(a,b,c) __builtin_amdgcn_mfma_f32_16x16x32_f16((a),(b),(c),0,0,0)

__device__ __forceinline__ float tanh_fast(float x){
    float e = __expf(2.f*x);
    return 1.f - 2.f*__builtin_amdgcn_rcpf(e + 1.f);
}

__device__ __forceinline__ f16x8 lds_rd8(const _Float16* b, int sB, int row, int colE){
    int off = row*sB + colE*2; off ^= (row&7)<<4;
    return *(const f16x8*)((const char*)b + off);
}
__device__ __forceinline__ void lds_wr1(_Float16* b, int sB, int row, int colE, float v){
    int off = row*sB + colE*2; off ^= (row&7)<<4;
    *(_Float16*)((char*)b + off) = (_Float16)v;
}

// B-frag gather from row-major fp32 W[K][N]: lane holds B[k0+8*(lane>>4)+i][n]
__device__ __forceinline__ f16x8 gbl_bfrag(const float* W, int ldN, int k0, int n){
    f16x8 f;
#pragma unroll
    for(int i=0;i<8;++i) f[i] = (_Float16)W[(size_t)(k0+i)*ldN + n];
    return f;
}

__global__ __launch_bounds__(512, 2) void ode_decoder_kernel(
    const float* __restrict__ z0, const float* __restrict__ times,
    const float* __restrict__ W1, const float* __restrict__ b1,
    const float* __restrict__ W2, const float* __restrict__ b2,
    const float* __restrict__ dW1, const float* __restrict__ db1,
    const float* __restrict__ dW2, const float* __restrict__ db2,
    const float* __restrict__ dW3, const float* __restrict__ db3,
    float* __restrict__ out)
{
    __shared__ _Float16 z_lds[16*LATENT]  __attribute__((aligned(16))); // 4 KB
    __shared__ _Float16 h_lds[16*HIDDEN]  __attribute__((aligned(16))); // 8 KB
    __shared__ _Float16 zint0[64*LATENT]  __attribute__((aligned(16))); // 16 KB (4 pts x 16 rows)
    __shared__ _Float16 zint1[64*LATENT]  __attribute__((aligned(16))); // 16 KB
    __shared__ _Float16 h1int[64*DECH]    __attribute__((aligned(16))); // 8 KB
    __shared__ _Float16 h2int[64*DECH]    __attribute__((aligned(16))); // 8 KB
    __shared__ float    tl[TT];

    const int tid  = threadIdx.x;
    const int wv   = tid >> 6;
    const int lane = tid & 63;
    const int lr   = lane & 15;
    const int lg   = lane >> 4;
    const int row0 = 4*lg;
    const int gRow0 = blockIdx.x * 16;
    const int nsl  = wv & 3;        // decoder n-slice for dG1/dG2
    const int mtb  = 2*(wv >> 2);   // decoder m-tile base for dG1/dG2

    if(tid < TT) tl[tid] = times[tid];

    // ---------- chain weights in VGPRs (R4-verified layout) ----------
    f16x8 w1f[2][4];
#pragma unroll
    for(int t=0;t<2;++t)
#pragma unroll
        for(int q=0;q<4;++q)
            w1f[t][q] = gbl_bfrag(W1, HIDDEN, 32*q+8*lg, 32*wv+16*t+lr);
    f16x8 w2f[8];
#pragma unroll
    for(int q=0;q<8;++q)
        w2f[q] = gbl_bfrag(W2, LATENT, 32*q+8*lg, 16*wv+lr);

    // ---------- decoder weights in VGPRs (R4 n-parallel slices, 8 frags/wave) ----------
    f16x8 dw1f[4], dw2f[2], dw3f[2];
#pragma unroll
    for(int q=0;q<4;++q) dw1f[q] = gbl_bfrag(dW1, DECH, 32*q+8*lg, 16*nsl+lr);
#pragma unroll
    for(int q=0;q<2;++q) dw2f[q] = gbl_bfrag(dW2, DECH, 32*q+8*lg, 16*nsl+lr);
#pragma unroll
    for(int q=0;q<2;++q) dw3f[q] = gbl_bfrag(dW3, OUTD, 32*q+8*lg, 16*wv+lr);

    const float b1v0 = b1[32*wv+lr], b1v1 = b1[32*wv+16+lr];
    const float b2v  = b2[16*wv+lr];
    const float db1v = db1[16*nsl+lr], db2v = db2[16*nsl+lr];
    const float db3v = db3[16*wv+lr];

    // ---------- state: lane owns z[row0+r][16*wv+lr] ----------
    f32x4 z, acc = {0,0,0,0};
    f32x4 zA = {0,0,0,0}, fA = {0,0,0,0}, fN = {0,0,0,0};
#pragma unroll
    for(int r=0;r<4;++r){
        z[r] = z0[(size_t)(gRow0+row0+r)*LATENT + 16*wv + lr];
        lds_wr1(z_lds, LATENT*2, row0+r, 16*wv+lr, z[r]);
    }
    __syncthreads();

    // ---------- chain segment bodies ----------
    auto G1SEG = [&]{
        f16x8 az[4];
#pragma unroll
        for(int q=0;q<4;++q) az[q] = lds_rd8(z_lds, LATENT*2, lr, 32*q+8*lg);
        f32x4 c0 = {b1v0,b1v0,b1v0,b1v0};
        f32x4 c1 = {b1v1,b1v1,b1v1,b1v1};
#pragma unroll
        for(int q=0;q<4;++q){ c0 = MFMA16(az[q], w1f[0][q], c0); c1 = MFMA16(az[q], w1f[1][q], c1); }
#pragma unroll
        for(int r=0;r<4;++r){
            lds_wr1(h_lds, HIDDEN*2, row0+r, 32*wv+lr,    tanh_fast(c0[r]));
            lds_wr1(h_lds, HIDDEN*2, row0+r, 32*wv+16+lr, tanh_fast(c1[r]));
        }
    };
    auto G2SEG = [&]() -> f32x4 {
        f16x8 ah[8];
#pragma unroll
        for(int q=0;q<8;++q) ah[q] = lds_rd8(h_lds, HIDDEN*2, lr, 32*q+8*lg);
        f32x4 ca = {b2v,b2v,b2v,b2v}, cb = {0,0,0,0};
#pragma unroll
        for(int q=0;q<4;++q){ ca = MFMA16(ah[q], w2f[q], ca); cb = MFMA16(ah[4+q], w2f[4+q], cb); }
        return ca + cb;
    };
    auto WRZ = [&](f32x4 zs){
#pragma unroll
        for(int r=0;r<4;++r) lds_wr1(z_lds, LATENT*2, row0+r, 16*wv+lr, zs[r]);
    };
    // Hermite dense output: 4 pts basePt.. of interval [t0,t0+hp] -> dst (pt i at rows 16i..)
    // endpoints: (zA,fA) at t0, (z,fN) at t0+hp
    auto INTERP4 = [&](_Float16* dst, int basePt, float t0, float hp, float rhp){
#pragma unroll
        for(int i=0;i<4;++i){
            float th = (tl[basePt+i]-t0)*rhp;
            float t2 = th*th, t3 = t2*th;
            float a0 = 2.f*t3-3.f*t2+1.f, a1 = (t3-2.f*t2+th)*hp;
            float a2 = 3.f*t2-2.f*t3,     a3 = (t3-t2)*hp;
#pragma unroll
            for(int r=0;r<4;++r){
                float v = a0*zA[r] + a1*fA[r] + a2*z[r] + a3*fN[r];
                lds_wr1(dst, LATENT*2, 16*i+row0+r, 16*wv+lr, v);
            }
        }
    };
    auto DG1 = [&](const _Float16* zsrc){   // wave: n-slice nsl, m-tiles mtb,mtb+1
#pragma unroll
        for(int m=0;m<2;++m){ int mt = mtb+m;
            f32x4 c = {db1v,db1v,db1v,db1v};
#pragma unroll
            for(int q=0;q<4;++q) c = MFMA16(lds_rd8(zsrc, LATENT*2, 16*mt+lr, 32*q+8*lg), dw1f[q], c);
#pragma unroll
            for(int r=0;r<4;++r) lds_wr1(h1int, DECH*2, 16*mt+row0+r, 16*nsl+lr, fmaxf(c[r],0.f));
        }
    };
    auto DG2 = [&]{
#pragma unroll
        for(int m=0;m<2;++m){ int mt = mtb+m;
            f32x4 c = {db2v,db2v,db2v,db2v};
#pragma unroll
            for(int q=0;q<2;++q) c = MFMA16(lds_rd8(h1int, DECH*2, 16*mt+lr, 32*q+8*lg), dw2f[q], c);
#pragma unroll
            for(int r=0;r<4;++r) lds_wr1(h2int, DECH*2, 16*mt+row0+r, 16*nsl+lr, fmaxf(c[r],0.f));
        }
    };
    auto DG3 = [&](int basePt){
#pragma unroll
        for(int mt=0;mt<4;++mt){
            f32x4 c = {db3v,db3v,db3v,db3v};
#pragma unroll
            for(int q=0;q<2;++q) c = MFMA16(lds_rd8(h2int, DECH*2, 16*mt+lr, 32*q+8*lg), dw3f[q], c);
#pragma unroll
            for(int r=0;r<4;++r)
                out[(size_t)(gRow0+row0+r)*TT*OUTD + (size_t)(basePt+mt)*OUTD + 16*wv+lr] = c[r];
        }
    };

    // ---------- main: 7 macro RK4 steps ----------
    // During macro j: decode interval j-1 (pts pP..pP+15) rounds A(s0b..s2a), B, C;
    // rounds C/D tails (DG3_C, DG1/DG2/DG3_D) of interval j-2 spill into s0a/s0b/s1a.
#pragma unroll 1
    for(int j=0;j<NMACRO;++j){
        const int  m0 = 16*j;
        const int  m1 = (m0+16 < TT-1) ? m0+16 : TT-1;
        const float hj = tl[m1]-tl[m0];
        const bool dA = (j>=1);
        const bool dD = (j>=2);
        const int  pP = 16*(j-1);
        const int  pQ = 16*(j-2);
        const float t0  = dA ? tl[pP] : 1.f;
        const float hp  = dA ? (tl[m0]-t0) : 1.f;
        const float rhp = 1.f/hp;

        // s0a
        G1SEG(); if(dD){ DG3(pQ+8); DG1(zint1); }          // DG3_C(j-2), DG1_D(j-2)
        __syncthreads();
        // s0b
        {
            f32x4 k1 = G2SEG();
            fN = k1;
            if(dD) DG2();                                   // DG2_D(j-2)
            if(dA){ INTERP4(zint0, pP, t0, hp, rhp);        // A
                    INTERP4(zint1, pP+4, t0, hp, rhp); }    // B
            acc = z + k1*(hj*(1.f/6.f));
            WRZ(z + k1*(hj*0.5f));
        }
        __syncthreads();
        // s1a
        G1SEG(); if(dD) DG3(pQ+12);                         // DG3_D(j-2)
        if(dA) DG1(zint0);                                  // DG1_A
        __syncthreads();
        // s1b
        {
            f32x4 k2 = G2SEG();
            if(dA){ DG2(); INTERP4(zint0, pP+8, t0, hp, rhp); }  // DG2_A, C
            acc += k2*(hj*(1.f/3.f));
            WRZ(z + k2*(hj*0.5f));
        }
        __syncthreads();
        // s2a
        G1SEG(); if(dA){ DG3(pP); DG1(zint1); }             // DG3_A, DG1_B
        __syncthreads();
        // s2b
        {
            f32x4 k3 = G2SEG();
            if(dA){ DG2(); INTERP4(zint1, pP+12, t0, hp, rhp); } // DG2_B, D
            zA = z; fA = fN;                                // after last INTERP of this macro
            acc += k3*(hj*(1.f/3.f));
            WRZ(z + k3*hj);
        }
        __syncthreads();
        // s3a
        G1SEG(); if(dA){ DG3(pP+4); DG1(zint0); }           // DG3_B, DG1_C
        __syncthreads();
        // s3b
        {
            f32x4 k4 = G2SEG(); if(dA) DG2();               // DG2_C
            z = acc + k4*(hj*(1.f/6.f));
            WRZ(z);
        }
        __syncthreads();
    }

    // ---------- tail ----------
    // pending: interval 5 spillover (DG3_C, DG1/DG2/DG3_D) + interval 6 (pts 96..99)
    {
        const int pQ = 16*(NMACRO-2);   // 80: interval 5 base
        const int pL = 16*(NMACRO-1);   // 96: interval 6 base
        // T1a
        G1SEG(); DG3(pQ+8); DG1(zint1);
        __syncthreads();
        // T1b
        {
            f32x4 k1 = G2SEG();
            fN = k1;
            DG2();
            const float t0t = tl[pL], hpt = tl[TT-1]-t0t, rhpt = 1.f/hpt;
            INTERP4(zint0, pL, t0t, hpt, rhpt);
        }
        __syncthreads();
        // T2a
        DG3(pQ+12); DG1(zint0);
        __syncthreads();
        // T2b
        DG2();
        __syncthreads();
        // T3a
        DG3(pL);
    }
}

extern "C" void kernel_launch(void* const* d_in, const int* in_sizes, int n_in,
                              void* d_out, int out_size, void* d_ws, size_t ws_size,
                              hipStream_t stream) {
    ode_decoder_kernel<<<dim3(256), dim3(512), 0, stream>>>(
        (const float*)d_in[0],  (const float*)d_in[1],
        (const float*)d_in[2],  (const float*)d_in[3],
        (const float*)d_in[4],  (const float*)d_in[5],
        (const float*)d_in[6],  (const float*)d_in[7],
        (const float*)d_in[8],  (const float*)d_in[9],
        (const float*)d_in[10], (const float*)d_in[11],
        (float*)d_out);
}